// Round 1
// baseline (306.999 us; speedup 1.0000x reference)
//
#include <hip/hip_runtime.h>

// Problem dims (fixed)
#define S_ 256
#define BSZ_ 64
#define IN_F_ 1024
#define OUT_F_ 512
#define USER_F_ 512

typedef short short8 __attribute__((ext_vector_type(8)));
typedef float f32x4 __attribute__((ext_vector_type(4)));

__device__ __forceinline__ ushort f2bf(float f) {
  unsigned u = __float_as_uint(f);
  unsigned r = (u + 0x7FFFu + ((u >> 16) & 1u)) >> 16;
  return (ushort)r;
}
__device__ __forceinline__ float bf2f(unsigned hi16) {
  return __uint_as_float(hi16 << 16);
}
__device__ __forceinline__ float sigf(float x) {
  return 1.f / (1.f + __expf(-x));
}

// ---------------- conversion kernels ----------------
__global__ void convert_bf16(const float* __restrict__ in, ushort* __restrict__ out, long n) {
  long i = ((long)blockIdx.x * blockDim.x + threadIdx.x) * 4;
  if (i + 3 < n) {
    float4 v = *(const float4*)(in + i);
    ushort4 o;
    o.x = f2bf(v.x); o.y = f2bf(v.y); o.z = f2bf(v.z); o.w = f2bf(v.w);
    *(ushort4*)(out + i) = o;
  }
}

// out[e*512+d] = bf16(W[d*512+e])  (transpose so GEMM3 can use the B^T template)
__global__ void convert_transpose_w(const float* __restrict__ in, ushort* __restrict__ out) {
  int i = blockIdx.x * blockDim.x + threadIdx.x;
  int e = i >> 9, d = i & 511;
  out[i] = f2bf(in[d * 512 + e]);
}

// ---------------- GEMM: C = A(MxK) * B(NxK)^T ----------------
// MODE 0: outf = acc + bias              (d_pre, f32)
// MODE 1: u_pre=acc+bias; d'=d_pre*sig(u_pre); u'=u_pre*sig(d'); dgout=bf16(d'); outb=bf16(u')
// MODE 2: outb = bf16(acc)               (t)
// MODE 3: outf = tanh(acc)               (att, batched via blockIdx.z)
#define BM 64
#define BN 64
#define BK 32
#define LDSK 40  // +8 bf16 pad: row stride 80B (16B-aligned, banks balanced)

template <int MODE>
__global__ __launch_bounds__(256) void gemm_bt(
    const ushort* __restrict__ Ag, const ushort* __restrict__ Bg,
    const float* __restrict__ bias,
    float* __restrict__ outf, ushort* __restrict__ outb,
    const float* __restrict__ dpre, ushort* __restrict__ dgout,
    int M, int N, int K, long zA, long zB, long zO) {
  __shared__ ushort As[BM][LDSK];
  __shared__ ushort Bs[BN][LDSK];
  const int z = blockIdx.z;
  const ushort* A = Ag + (long)z * zA;
  const ushort* B = Bg + (long)z * zB;
  const int m0 = blockIdx.y * BM, n0 = blockIdx.x * BN;
  const int tid = threadIdx.x;
  const int lane = tid & 63, wave = tid >> 6;
  const int srow = tid >> 2;          // staging row 0..63
  const int skc = (tid & 3) * 8;      // staging k-chunk 0/8/16/24
  const int mlane = lane & 15;
  const int q = lane >> 4;            // quad -> k offset q*8 (A/B), row q*4+i (C/D)

  f32x4 acc[4];
#pragma unroll
  for (int j = 0; j < 4; ++j) {
    acc[j][0] = 0.f; acc[j][1] = 0.f; acc[j][2] = 0.f; acc[j][3] = 0.f;
  }

  for (int k0 = 0; k0 < K; k0 += BK) {
    uint4 av = *(const uint4*)(A + (long)(m0 + srow) * K + (k0 + skc));
    uint4 bv = *(const uint4*)(B + (long)(n0 + srow) * K + (k0 + skc));
    *(uint4*)&As[srow][skc] = av;
    *(uint4*)&Bs[srow][skc] = bv;
    __syncthreads();
    short8 af = *(const short8*)&As[wave * 16 + mlane][q * 8];
#pragma unroll
    for (int j = 0; j < 4; ++j) {
      short8 bf = *(const short8*)&Bs[j * 16 + mlane][q * 8];
      acc[j] = __builtin_amdgcn_mfma_f32_16x16x32_bf16(af, bf, acc[j], 0, 0, 0);
    }
    __syncthreads();
  }

#pragma unroll
  for (int j = 0; j < 4; ++j) {
    const int gn = n0 + j * 16 + mlane;
#pragma unroll
    for (int i = 0; i < 4; ++i) {
      const int gm = m0 + wave * 16 + q * 4 + i;
      const long idx = (long)z * zO + (long)gm * N + gn;
      const float v = acc[j][i];
      if (MODE == 0) {
        outf[idx] = v + bias[gn];
      } else if (MODE == 1) {
        float up = v + bias[gn];
        float dp = dpre[idx];
        float dgv = dp * sigf(up);
        float ugv = up * sigf(dgv);
        dgout[idx] = f2bf(dgv);
        outb[idx] = f2bf(ugv);
      } else if (MODE == 2) {
        outb[idx] = f2bf(v);
      } else {
        outf[idx] = tanhf(v);
      }
    }
  }
}

// ---------------- finalize: means -> softmax -> weighted sums ----------------
__device__ __forceinline__ float block_max(float v, float* buf, int tid) {
  buf[tid] = v; __syncthreads();
  for (int s = 128; s > 0; s >>= 1) {
    if (tid < s) buf[tid] = fmaxf(buf[tid], buf[tid + s]);
    __syncthreads();
  }
  float r = buf[0]; __syncthreads();
  return r;
}
__device__ __forceinline__ float block_sum(float v, float* buf, int tid) {
  buf[tid] = v; __syncthreads();
  for (int s = 128; s > 0; s >>= 1) {
    if (tid < s) buf[tid] = buf[tid] + buf[tid + s];
    __syncthreads();
  }
  float r = buf[0]; __syncthreads();
  return r;
}

__global__ __launch_bounds__(256) void finalize(
    const float* __restrict__ att, const ushort* __restrict__ dg,
    const ushort* __restrict__ ug, float* __restrict__ out) {
  __shared__ float sd[S_], su[S_], buf[S_];
  const int b = blockIdx.x, tid = threadIdx.x;
  const float* attb = att + (long)b * (S_ * S_);

  float colacc = 0.f, rowacc = 0.f;
  for (int s = 0; s < S_; ++s) colacc += attb[s * S_ + tid];   // mean over axis s -> logit over r
  for (int r = 0; r < S_; ++r) rowacc += attb[tid * S_ + r];   // mean over axis r -> logit over s
  const float rowmean = rowacc * (1.f / (float)S_);
  const float colmean = colacc * (1.f / (float)S_);

  // softmax over s (score_d)
  float md = block_max(rowmean, buf, tid);
  float ed = __expf(rowmean - md);
  float sds = block_sum(ed, buf, tid);
  sd[tid] = ed / sds;
  // softmax over r (score_u)
  float mu = block_max(colmean, buf, tid);
  float eu = __expf(colmean - mu);
  float sus = block_sum(eu, buf, tid);
  su[tid] = eu / sus;
  __syncthreads();

  // attention_d[b,o] = sum_s sd[s]*d'[b,s,o] ; attention_u[b,o] = sum_r su[r]*u'[b,r,o]
  const ushort* dgb = dg + (long)b * (S_ * OUT_F_);
  const ushort* ugb = ug + (long)b * (S_ * OUT_F_);
  float ad0 = 0.f, ad1 = 0.f, au0 = 0.f, au1 = 0.f;
  const int o = 2 * tid;
  for (int s = 0; s < S_; ++s) {
    const float wd = sd[s], wu = su[s];
    unsigned dv = *(const unsigned*)(dgb + s * OUT_F_ + o);
    unsigned uv = *(const unsigned*)(ugb + s * OUT_F_ + o);
    ad0 += wd * bf2f(dv & 0xffffu); ad1 += wd * bf2f(dv >> 16);
    au0 += wu * bf2f(uv & 0xffffu); au1 += wu * bf2f(uv >> 16);
  }
  out[b * OUT_F_ + o] = ad0;
  out[b * OUT_F_ + o + 1] = ad1;
  out[BSZ_ * OUT_F_ + b * OUT_F_ + o] = au0;
  out[BSZ_ * OUT_F_ + b * OUT_F_ + o + 1] = au1;
}

extern "C" void kernel_launch(void* const* d_in, const int* in_sizes, int n_in,
                              void* d_out, int out_size, void* d_ws, size_t ws_size,
                              hipStream_t stream) {
  (void)in_sizes; (void)n_in; (void)out_size; (void)ws_size;
  const float* Xd = (const float*)d_in[0];
  const float* Xu = (const float*)d_in[1];
  const float* Wd = (const float*)d_in[2];
  const float* bd = (const float*)d_in[3];
  const float* Wu = (const float*)d_in[4];
  const float* bu = (const float*)d_in[5];
  const float* W  = (const float*)d_in[6];
  float* out = (float*)d_out;
  char* ws = (char*)d_ws;

  // workspace layout (bytes, all 256-aligned). Peak ~114 MB.
  ushort* Xd_bf = (ushort*)(ws + 0L);           // 33,554,432
  ushort* Xu_bf = (ushort*)(ws + 33554432L);    // 16,777,216
  ushort* Wd_bf = (ushort*)(ws + 50331648L);    //  1,048,576
  ushort* Wu_bf = (ushort*)(ws + 51380224L);    //    524,288
  ushort* Wt_bf = (ushort*)(ws + 51904512L);    //    524,288
  float*  dpre  = (float*)(ws + 52428800L);     // 33,554,432 (dead after gemm<1>)
  ushort* t_bf  = (ushort*)(ws + 52428800L);    // 16,777,216 (reuse of dpre[0:half])
  float*  att   = (float*)(ws + 69206016L);     // 16,777,216 (reuse of dpre[half:])
  ushort* dg    = (ushort*)(ws + 85983232L);    // 16,777,216
  ushort* ug    = (ushort*)(ws + 102760448L);   // 16,777,216

  convert_bf16<<<16384, 256, 0, stream>>>(Xd, Xd_bf, 16777216L);
  convert_bf16<<<8192, 256, 0, stream>>>(Xu, Xu_bf, 8388608L);
  convert_bf16<<<512, 256, 0, stream>>>(Wd, Wd_bf, 524288L);
  convert_bf16<<<256, 256, 0, stream>>>(Wu, Wu_bf, 262144L);
  convert_transpose_w<<<1024, 256, 0, stream>>>(W, Wt_bf);

  dim3 blk(256);
  // d_pre = Xd * Wd^T + bd     (M=16384,N=512,K=1024)
  gemm_bt<0><<<dim3(8, 256, 1), blk, 0, stream>>>(Xd_bf, Wd_bf, bd, dpre, nullptr,
                                                  nullptr, nullptr, 16384, 512, 1024, 0, 0, 0);
  // u_pre = Xu * Wu^T + bu; gating -> dg, ug (bf16)
  gemm_bt<1><<<dim3(8, 256, 1), blk, 0, stream>>>(Xu_bf, Wu_bf, bu, nullptr, ug,
                                                  dpre, dg, 16384, 512, 512, 0, 0, 0);
  // t = d' * W  (via W^T stored as N x K)
  gemm_bt<2><<<dim3(8, 256, 1), blk, 0, stream>>>(dg, Wt_bf, nullptr, nullptr, t_bf,
                                                  nullptr, nullptr, 16384, 512, 512, 0, 0, 0);
  // att = tanh(t * u'^T), batched over b
  gemm_bt<3><<<dim3(4, 4, 64), blk, 0, stream>>>(t_bf, ug, nullptr, att, nullptr,
                                                 nullptr, nullptr, 256, 256, 512,
                                                 131072L, 131072L, 65536L);
  finalize<<<64, 256, 0, stream>>>(att, dg, ug, out);
}

// Round 2
// 294.637 us; speedup vs baseline: 1.0420x; 1.0420x over previous
//
#include <hip/hip_runtime.h>

// Problem dims (fixed)
#define S_ 256
#define BSZ_ 64
#define IN_F_ 1024
#define OUT_F_ 512
#define USER_F_ 512

typedef short short8 __attribute__((ext_vector_type(8)));
typedef float f32x4 __attribute__((ext_vector_type(4)));

__device__ __forceinline__ ushort f2bf(float f) {
  unsigned u = __float_as_uint(f);
  unsigned r = (u + 0x7FFFu + ((u >> 16) & 1u)) >> 16;
  return (ushort)r;
}
__device__ __forceinline__ float bf2f(unsigned hi16) {
  return __uint_as_float(hi16 << 16);
}
__device__ __forceinline__ float sigf(float x) {
  return 1.f / (1.f + __expf(-x));
}
__device__ __forceinline__ float tanh_fast(float x) {
  // tanh(x) = (e^2x - 1)/(e^2x + 1); bf16-level accuracy is plenty
  float e = __expf(2.f * x);
  return (e - 1.f) / (e + 1.f);
}

// async global->LDS, 16B per lane; LDS dest = wave-uniform base + lane*16
__device__ __forceinline__ void gl_lds16(const ushort* g, ushort* l) {
  __builtin_amdgcn_global_load_lds(
      (const __attribute__((address_space(1))) void*)g,
      (__attribute__((address_space(3))) void*)l, 16, 0, 0);
}

// ---------------- conversion kernels ----------------
__global__ void convert_bf16(const float* __restrict__ in, ushort* __restrict__ out, long n) {
  long i = ((long)blockIdx.x * blockDim.x + threadIdx.x) * 4;
  if (i + 3 < n) {
    float4 v = *(const float4*)(in + i);
    ushort4 o;
    o.x = f2bf(v.x); o.y = f2bf(v.y); o.z = f2bf(v.z); o.w = f2bf(v.w);
    *(ushort4*)(out + i) = o;
  }
}

// out[e*512+d] = bf16(W[d*512+e])  (transpose so GEMM3 can use the B^T template)
__global__ void convert_transpose_w(const float* __restrict__ in, ushort* __restrict__ out) {
  int i = blockIdx.x * blockDim.x + threadIdx.x;
  int e = i >> 9, d = i & 511;
  out[i] = f2bf(in[d * 512 + e]);
}

// ---------------- 128x128 GEMM: C = A(MxK) * B(NxK)^T ----------------
// m97 structure: BK=32, global_load_lds(16B) staging, 4 waves (2x2), each wave
// 4x4 accs of 16x16x32 MFMA. LDS unpadded [128][32] (global_load_lds requires
// lane-contiguous layout; +pad would scatter lanes into the pad).
// MODE 0: outf = acc + bias              (d_pre, f32)
// MODE 1: u_pre=acc+bias; d'=dpre*sig(u_pre); u'=u_pre*sig(d'); dgout=bf16(d'); outb=bf16(u')
// MODE 2: outb = bf16(acc)               (t)
// MODE 3: outf = tanh(acc)               (att, batched via blockIdx.z)
template <int MODE>
__global__ __launch_bounds__(256) void gemm128(
    const ushort* __restrict__ Ag, const ushort* __restrict__ Bg,
    const float* __restrict__ bias,
    float* __restrict__ outf, ushort* __restrict__ outb,
    const float* __restrict__ dpre, ushort* __restrict__ dgout,
    int M, int N, int K, long zA, long zB, long zO) {
  __shared__ ushort As[128 * 32];
  __shared__ ushort Bs[128 * 32];
  const int z = blockIdx.z;
  const ushort* A = Ag + (long)z * zA + (long)blockIdx.y * 128 * K;
  const ushort* B = Bg + (long)z * zB + (long)blockIdx.x * 128 * K;
  const int tid = threadIdx.x;
  const int lane = tid & 63, w = tid >> 6;
  const int wr = w >> 1, wc = w & 1;      // wave at (wr,wc), covers 64x64
  const int mlane = lane & 15, q = lane >> 4;

  // staging: wave w owns bytes [w*2048, w*2048+2048) of each 8KB tile,
  // as 2 chunks of 1KB (64 lanes x 16B). row = w*32 + chunk*16 + lane/4.
  const int srow = w * 32 + (lane >> 2);
  const int skc = (lane & 3) * 8;
  const ushort* a0 = A + (long)srow * K + skc;
  const ushort* b0 = B + (long)srow * K + skc;
  ushort* ldsA = As + w * 1024;  // wave-uniform
  ushort* ldsB = Bs + w * 1024;

  f32x4 acc[4][4];
#pragma unroll
  for (int r = 0; r < 4; ++r)
#pragma unroll
    for (int c = 0; c < 4; ++c) {
      acc[r][c][0] = 0.f; acc[r][c][1] = 0.f; acc[r][c][2] = 0.f; acc[r][c][3] = 0.f;
    }

  for (int k0 = 0; k0 < K; k0 += 32) {
    gl_lds16(a0 + k0, ldsA);
    gl_lds16(a0 + (long)16 * K + k0, ldsA + 512);
    gl_lds16(b0 + k0, ldsB);
    gl_lds16(b0 + (long)16 * K + k0, ldsB + 512);
    __syncthreads();  // compiler emits vmcnt(0) drain before barrier

    short8 af[4], bfr[4];
#pragma unroll
    for (int r = 0; r < 4; ++r)
      af[r] = *(const short8*)&As[(wr * 64 + r * 16 + mlane) * 32 + q * 8];
#pragma unroll
    for (int c = 0; c < 4; ++c)
      bfr[c] = *(const short8*)&Bs[(wc * 64 + c * 16 + mlane) * 32 + q * 8];
#pragma unroll
    for (int r = 0; r < 4; ++r)
#pragma unroll
      for (int c = 0; c < 4; ++c)
        acc[r][c] = __builtin_amdgcn_mfma_f32_16x16x32_bf16(af[r], bfr[c], acc[r][c], 0, 0, 0);
    __syncthreads();
  }

#pragma unroll
  for (int c = 0; c < 4; ++c) {
    const int gn = blockIdx.x * 128 + wc * 64 + c * 16 + mlane;
    const float bv = (MODE <= 1) ? bias[gn] : 0.f;
#pragma unroll
    for (int r = 0; r < 4; ++r) {
#pragma unroll
      for (int i = 0; i < 4; ++i) {
        const int gm = blockIdx.y * 128 + wr * 64 + r * 16 + q * 4 + i;
        const long idx = (long)z * zO + (long)gm * N + gn;
        const float v = acc[r][c][i];
        if (MODE == 0) {
          outf[idx] = v + bv;
        } else if (MODE == 1) {
          float up = v + bv;
          float dp = dpre[idx];
          float dgv = dp * sigf(up);
          float ugv = up * sigf(dgv);
          dgout[idx] = f2bf(dgv);
          outb[idx] = f2bf(ugv);
        } else if (MODE == 2) {
          outb[idx] = f2bf(v);
        } else {
          outf[idx] = tanh_fast(v);
        }
      }
    }
  }
}

// ---------------- finalize: means -> softmax -> weighted sums ----------------
__device__ __forceinline__ float block_max(float v, float* buf, int tid) {
  buf[tid] = v; __syncthreads();
  for (int s = 128; s > 0; s >>= 1) {
    if (tid < s) buf[tid] = fmaxf(buf[tid], buf[tid + s]);
    __syncthreads();
  }
  float r = buf[0]; __syncthreads();
  return r;
}
__device__ __forceinline__ float block_sum(float v, float* buf, int tid) {
  buf[tid] = v; __syncthreads();
  for (int s = 128; s > 0; s >>= 1) {
    if (tid < s) buf[tid] = buf[tid] + buf[tid + s];
    __syncthreads();
  }
  float r = buf[0]; __syncthreads();
  return r;
}

__global__ __launch_bounds__(256) void finalize(
    const float* __restrict__ att, const ushort* __restrict__ dg,
    const ushort* __restrict__ ug, float* __restrict__ out) {
  __shared__ float sd[S_], su[S_], buf[S_];
  const int b = blockIdx.x, tid = threadIdx.x;
  const float* attb = att + (long)b * (S_ * S_);

  float colacc = 0.f, rowacc = 0.f;
  for (int s = 0; s < S_; ++s) colacc += attb[s * S_ + tid];   // logit over r
  for (int r = 0; r < S_; ++r) rowacc += attb[tid * S_ + r];   // logit over s
  const float rowmean = rowacc * (1.f / (float)S_);
  const float colmean = colacc * (1.f / (float)S_);

  float md = block_max(rowmean, buf, tid);
  float ed = __expf(rowmean - md);
  float sds = block_sum(ed, buf, tid);
  sd[tid] = ed / sds;
  float mu = block_max(colmean, buf, tid);
  float eu = __expf(colmean - mu);
  float sus = block_sum(eu, buf, tid);
  su[tid] = eu / sus;
  __syncthreads();

  const ushort* dgb = dg + (long)b * (S_ * OUT_F_);
  const ushort* ugb = ug + (long)b * (S_ * OUT_F_);
  float ad0 = 0.f, ad1 = 0.f, au0 = 0.f, au1 = 0.f;
  const int o = 2 * tid;
  for (int s = 0; s < S_; ++s) {
    const float wd = sd[s], wu = su[s];
    unsigned dv = *(const unsigned*)(dgb + s * OUT_F_ + o);
    unsigned uv = *(const unsigned*)(ugb + s * OUT_F_ + o);
    ad0 += wd * bf2f(dv & 0xffffu); ad1 += wd * bf2f(dv >> 16);
    au0 += wu * bf2f(uv & 0xffffu); au1 += wu * bf2f(uv >> 16);
  }
  out[b * OUT_F_ + o] = ad0;
  out[b * OUT_F_ + o + 1] = ad1;
  out[BSZ_ * OUT_F_ + b * OUT_F_ + o] = au0;
  out[BSZ_ * OUT_F_ + b * OUT_F_ + o + 1] = au1;
}

extern "C" void kernel_launch(void* const* d_in, const int* in_sizes, int n_in,
                              void* d_out, int out_size, void* d_ws, size_t ws_size,
                              hipStream_t stream) {
  (void)in_sizes; (void)n_in; (void)out_size; (void)ws_size;
  const float* Xd = (const float*)d_in[0];
  const float* Xu = (const float*)d_in[1];
  const float* Wd = (const float*)d_in[2];
  const float* bd = (const float*)d_in[3];
  const float* Wu = (const float*)d_in[4];
  const float* bu = (const float*)d_in[5];
  const float* W  = (const float*)d_in[6];
  float* out = (float*)d_out;
  char* ws = (char*)d_ws;

  // workspace layout (bytes, all 256-aligned). Peak ~114 MB.
  ushort* Xd_bf = (ushort*)(ws + 0L);           // 33,554,432
  ushort* Xu_bf = (ushort*)(ws + 33554432L);    // 16,777,216
  ushort* Wd_bf = (ushort*)(ws + 50331648L);    //  1,048,576
  ushort* Wu_bf = (ushort*)(ws + 51380224L);    //    524,288
  ushort* Wt_bf = (ushort*)(ws + 51904512L);    //    524,288
  float*  dpre  = (float*)(ws + 52428800L);     // 33,554,432 (dead after gemm<1>)
  ushort* t_bf  = (ushort*)(ws + 52428800L);    // 16,777,216 (reuse of dpre[0:half])
  float*  att   = (float*)(ws + 69206016L);     // 16,777,216 (reuse of dpre[half:])
  ushort* dg    = (ushort*)(ws + 85983232L);    // 16,777,216
  ushort* ug    = (ushort*)(ws + 102760448L);   // 16,777,216

  convert_bf16<<<16384, 256, 0, stream>>>(Xd, Xd_bf, 16777216L);
  convert_bf16<<<8192, 256, 0, stream>>>(Xu, Xu_bf, 8388608L);
  convert_bf16<<<512, 256, 0, stream>>>(Wd, Wd_bf, 524288L);
  convert_bf16<<<256, 256, 0, stream>>>(Wu, Wu_bf, 262144L);
  convert_transpose_w<<<1024, 256, 0, stream>>>(W, Wt_bf);

  dim3 blk(256);
  // d_pre = Xd * Wd^T + bd     (M=16384,N=512,K=1024)
  gemm128<0><<<dim3(4, 128, 1), blk, 0, stream>>>(Xd_bf, Wd_bf, bd, dpre, nullptr,
                                                  nullptr, nullptr, 16384, 512, 1024, 0, 0, 0);
  // u_pre = Xu * Wu^T + bu; gating -> dg, ug (bf16)
  gemm128<1><<<dim3(4, 128, 1), blk, 0, stream>>>(Xu_bf, Wu_bf, bu, nullptr, ug,
                                                  dpre, dg, 16384, 512, 512, 0, 0, 0);
  // t = d' * W  (via W^T stored as N x K)
  gemm128<2><<<dim3(4, 128, 1), blk, 0, stream>>>(dg, Wt_bf, nullptr, nullptr, t_bf,
                                                  nullptr, nullptr, 16384, 512, 512, 0, 0, 0);
  // att = tanh(t * u'^T), batched over b
  gemm128<3><<<dim3(2, 2, 64), blk, 0, stream>>>(t_bf, ug, nullptr, att, nullptr,
                                                 nullptr, nullptr, 256, 256, 512,
                                                 131072L, 131072L, 65536L);
  finalize<<<64, 256, 0, stream>>>(att, dg, ug, out);
}

// Round 3
// 234.777 us; speedup vs baseline: 1.3076x; 1.2550x over previous
//
#include <hip/hip_runtime.h>

// Problem dims (fixed)
#define S_ 256
#define BSZ_ 64
#define IN_F_ 1024
#define OUT_F_ 512
#define USER_F_ 512

typedef short short8 __attribute__((ext_vector_type(8)));
typedef float f32x4 __attribute__((ext_vector_type(4)));

__device__ __forceinline__ ushort f2bf(float f) {
  unsigned u = __float_as_uint(f);
  unsigned r = (u + 0x7FFFu + ((u >> 16) & 1u)) >> 16;
  return (ushort)r;
}
__device__ __forceinline__ float bf2f(unsigned hi16) {
  return __uint_as_float(hi16 << 16);
}
__device__ __forceinline__ float sigf(float x) {
  return 1.f / (1.f + __expf(-x));
}
__device__ __forceinline__ float tanh_safe(float x) {
  // no-overflow form: tanh(x) = sign(x) * (1 - e^-2|x|)/(1 + e^-2|x|)
  float ax = fabsf(x);
  float e = __expf(-2.f * ax);
  float r = (1.f - e) / (1.f + e);
  return copysignf(r, x);
}

// async global->LDS, 16B per lane; LDS dest = wave-uniform base + lane*16
__device__ __forceinline__ void gl_lds16(const ushort* g, ushort* l) {
  __builtin_amdgcn_global_load_lds(
      (const __attribute__((address_space(1))) void*)g,
      (__attribute__((address_space(3))) void*)l, 16, 0, 0);
}

// ---------------- conversion kernels ----------------
__global__ void convert_bf16(const float* __restrict__ in, ushort* __restrict__ out, long n) {
  long i = ((long)blockIdx.x * blockDim.x + threadIdx.x) * 4;
  if (i + 3 < n) {
    float4 v = *(const float4*)(in + i);
    ushort4 o;
    o.x = f2bf(v.x); o.y = f2bf(v.y); o.z = f2bf(v.z); o.w = f2bf(v.w);
    *(ushort4*)(out + i) = o;
  }
}

// out[e*512+d] = bf16(W[d*512+e])
__global__ void convert_transpose_w(const float* __restrict__ in, ushort* __restrict__ out) {
  int i = blockIdx.x * blockDim.x + threadIdx.x;
  int e = i >> 9, d = i & 511;
  out[i] = f2bf(in[d * 512 + e]);
}

__global__ void zerof(float* __restrict__ p, int n) {
  int i = blockIdx.x * 256 + threadIdx.x;
  if (i < n) p[i] = 0.f;
}

// ---------------- shared GEMM machinery (128x128 tile, BK=64, dbuf) ----------------
// LDS tile: 128 rows x 64 bf16 = 16KB. Physical chunk pc = c ^ (row&7)
// (XOR swizzle applied on the GLOBAL side so global_load_lds's
// lane-contiguous LDS dest is preserved). Makes ds_read_b128 conflict-free:
// each of 8 bank-groups hit exactly 8x = minimum for b128.
__device__ __forceinline__ void stage_tile(const ushort* __restrict__ g, int K,
                                           ushort* lds, int w, int lane) {
  const int rin = lane >> 3;      // 0..7 row within 8-row chunk
  const int c = lane & 7;         // lds 16B-chunk index within row
#pragma unroll
  for (int i = 0; i < 4; ++i) {
    int r = w * 32 + i * 8 + rin;
    int gc = c ^ (r & 7);         // global chunk that belongs at lds slot c
    gl_lds16(g + (long)r * K + gc * 8, lds + w * 2048 + i * 512);
  }
}

__device__ __forceinline__ short8 frag(const ushort* lds, int row, int kk, int q) {
  int pc = (kk * 4 + q) ^ (row & 7);
  return *(const short8*)(lds + row * 64 + pc * 8);
}

__device__ __forceinline__ void compute_step(const ushort* As, const ushort* Bs,
                                             f32x4 acc[4][4], int wr, int wc,
                                             int mlane, int q) {
#pragma unroll
  for (int kk = 0; kk < 2; ++kk) {
    short8 af[4], bfr[4];
#pragma unroll
    for (int r = 0; r < 4; ++r) af[r] = frag(As, wr * 64 + r * 16 + mlane, kk, q);
#pragma unroll
    for (int c = 0; c < 4; ++c) bfr[c] = frag(Bs, wc * 64 + c * 16 + mlane, kk, q);
#pragma unroll
    for (int r = 0; r < 4; ++r)
#pragma unroll
      for (int c = 0; c < 4; ++c)
        acc[r][c] = __builtin_amdgcn_mfma_f32_16x16x32_bf16(af[r], bfr[c], acc[r][c], 0, 0, 0);
  }
}

// K-loop with prefetch-across-barrier double buffer. One barrier per step:
// prefetch for k+1 issued AFTER the barrier, drained at the NEXT barrier —
// its HBM latency overlaps step k's ds_read+MFMA. NSTEP must be even.
template <int NSTEP>
__device__ __forceinline__ void gemm_loop(const ushort* __restrict__ A,
                                          const ushort* __restrict__ B, int K,
                                          ushort* As0, ushort* Bs0,
                                          ushort* As1, ushort* Bs1,
                                          f32x4 acc[4][4], int w, int lane,
                                          int wr, int wc, int mlane, int q) {
  stage_tile(A, K, As0, w, lane);
  stage_tile(B, K, Bs0, w, lane);
#pragma unroll 1
  for (int k = 0; k < NSTEP; k += 2) {
    __syncthreads();  // drains buf0 loads (vmcnt0) + guards buf0 reuse
    if (k + 1 < NSTEP) {
      stage_tile(A + (k + 1) * 64, K, As1, w, lane);
      stage_tile(B + (k + 1) * 64, K, Bs1, w, lane);
    }
    compute_step(As0, Bs0, acc, wr, wc, mlane, q);
    __syncthreads();  // drains buf1 loads + guards buf1 reuse
    if (k + 2 < NSTEP) {
      stage_tile(A + (k + 2) * 64, K, As0, w, lane);
      stage_tile(B + (k + 2) * 64, K, Bs0, w, lane);
    }
    if (k + 1 < NSTEP) compute_step(As1, Bs1, acc, wr, wc, mlane, q);
  }
  __syncthreads();  // LDS safe for reuse by caller
}

#define ACC_ZERO(a)                         \
  _Pragma("unroll") for (int r = 0; r < 4; ++r) \
  _Pragma("unroll") for (int c = 0; c < 4; ++c) { \
    a[r][c][0] = 0.f; a[r][c][1] = 0.f; a[r][c][2] = 0.f; a[r][c][3] = 0.f; }

// ---------------- fused d/u GEMM + gating ----------------
// accd = Xd*Wd^T (K=1024); accu = Xu*Wu^T (K=512); gate; write dg,ug bf16.
__global__ __launch_bounds__(256, 2) void gemm_du(
    const ushort* __restrict__ Xd, const ushort* __restrict__ Wd,
    const float* __restrict__ bd,
    const ushort* __restrict__ Xu, const ushort* __restrict__ Wu,
    const float* __restrict__ bu,
    ushort* __restrict__ dg, ushort* __restrict__ ug) {
  __shared__ ushort sm[32768];  // 64KB: As0 Bs0 As1 Bs1 (8K shorts each)
  ushort* As0 = sm; ushort* Bs0 = sm + 8192;
  ushort* As1 = sm + 16384; ushort* Bs1 = sm + 24576;
  const int tid = threadIdx.x, lane = tid & 63, w = tid >> 6;
  const int wr = w >> 1, wc = w & 1, mlane = lane & 15, q = lane >> 4;
  const int m0 = blockIdx.y * 128, n0 = blockIdx.x * 128;

  f32x4 accd[4][4]; ACC_ZERO(accd);
  gemm_loop<16>(Xd + (long)m0 * 1024, Wd + (long)n0 * 1024, 1024,
                As0, Bs0, As1, Bs1, accd, w, lane, wr, wc, mlane, q);
  f32x4 accu[4][4]; ACC_ZERO(accu);
  gemm_loop<8>(Xu + (long)m0 * 512, Wu + (long)n0 * 512, 512,
               As0, Bs0, As1, Bs1, accu, w, lane, wr, wc, mlane, q);

#pragma unroll
  for (int c = 0; c < 4; ++c) {
    const int gn = n0 + wc * 64 + c * 16 + mlane;
    const float bdv = bd[gn], buv = bu[gn];
#pragma unroll
    for (int r = 0; r < 4; ++r)
#pragma unroll
      for (int i = 0; i < 4; ++i) {
        const int gm = m0 + wr * 64 + r * 16 + q * 4 + i;
        const long idx = (long)gm * OUT_F_ + gn;
        float dp = accd[r][c][i] + bdv;
        float up = accu[r][c][i] + buv;
        float dgv = dp * sigf(up);
        float ugv = up * sigf(dgv);
        dg[idx] = f2bf(dgv);
        ug[idx] = f2bf(ugv);
      }
  }
}

// ---------------- t = dg * Wt^T ----------------
__global__ __launch_bounds__(256, 2) void gemm_t(
    const ushort* __restrict__ dgp, const ushort* __restrict__ Wt,
    ushort* __restrict__ tout) {
  __shared__ ushort sm[32768];
  ushort* As0 = sm; ushort* Bs0 = sm + 8192;
  ushort* As1 = sm + 16384; ushort* Bs1 = sm + 24576;
  const int tid = threadIdx.x, lane = tid & 63, w = tid >> 6;
  const int wr = w >> 1, wc = w & 1, mlane = lane & 15, q = lane >> 4;
  const int m0 = blockIdx.y * 128, n0 = blockIdx.x * 128;

  f32x4 acc[4][4]; ACC_ZERO(acc);
  gemm_loop<8>(dgp + (long)m0 * 512, Wt + (long)n0 * 512, 512,
               As0, Bs0, As1, Bs1, acc, w, lane, wr, wc, mlane, q);

#pragma unroll
  for (int c = 0; c < 4; ++c) {
    const int gn = n0 + wc * 64 + c * 16 + mlane;
#pragma unroll
    for (int r = 0; r < 4; ++r)
#pragma unroll
      for (int i = 0; i < 4; ++i) {
        const int gm = m0 + wr * 64 + r * 16 + q * 4 + i;
        tout[(long)gm * OUT_F_ + gn] = f2bf(acc[r][c][i]);
      }
  }
}

// ---------------- att tile + tanh + row/col sums (att never materialized) ----
// rowlog[b][s] += sum_r tanh(att[s,r]);  collog[b][r] += sum_s tanh(att[s,r])
__global__ __launch_bounds__(256, 2) void gemm_att(
    const ushort* __restrict__ t, const ushort* __restrict__ ug,
    float* __restrict__ rowlog, float* __restrict__ collog) {
  __shared__ ushort sm[32768];
  ushort* As0 = sm; ushort* Bs0 = sm + 8192;
  ushort* As1 = sm + 16384; ushort* Bs1 = sm + 24576;
  const int tid = threadIdx.x, lane = tid & 63, w = tid >> 6;
  const int wr = w >> 1, wc = w & 1, mlane = lane & 15, q = lane >> 4;
  const int b = blockIdx.z;
  const ushort* A = t + (long)b * (S_ * OUT_F_) + (long)blockIdx.y * 128 * 512;
  const ushort* B = ug + (long)b * (S_ * OUT_F_) + (long)blockIdx.x * 128 * 512;

  f32x4 acc[4][4]; ACC_ZERO(acc);
  gemm_loop<8>(A, B, 512, As0, Bs0, As1, Bs1, acc, w, lane, wr, wc, mlane, q);

  // tanh + per-lane partials
  float rs[4][4];  // [r][i]: sum over this lane's 4 cols, for row r*16+q*4+i
  float cs[4];     // [c]:    sum over this lane's 16 rows, for col c*16+mlane
#pragma unroll
  for (int r = 0; r < 4; ++r)
#pragma unroll
    for (int i = 0; i < 4; ++i) rs[r][i] = 0.f;
#pragma unroll
  for (int c = 0; c < 4; ++c) cs[c] = 0.f;
#pragma unroll
  for (int r = 0; r < 4; ++r)
#pragma unroll
    for (int c = 0; c < 4; ++c)
#pragma unroll
      for (int i = 0; i < 4; ++i) {
        float v = tanh_safe(acc[r][c][i]);
        rs[r][i] += v;
        cs[c] += v;
      }
  // rows: reduce across mlane (16 lanes share a row-set)
#pragma unroll
  for (int m = 1; m < 16; m <<= 1)
#pragma unroll
    for (int r = 0; r < 4; ++r)
#pragma unroll
      for (int i = 0; i < 4; ++i) rs[r][i] += __shfl_xor(rs[r][i], m, 64);
  // cols: reduce across q (4 lane-quads share a col-set)
#pragma unroll
  for (int m = 16; m < 64; m <<= 1)
#pragma unroll
    for (int c = 0; c < 4; ++c) cs[c] += __shfl_xor(cs[c], m, 64);

  // LDS accumulate across the 4 waves (tiles are dead; alias LDS)
  float* rsum = (float*)sm;          // [128]
  float* csum = ((float*)sm) + 128;  // [128]
  if (tid < 128) rsum[tid] = 0.f;
  else if (tid < 256) csum[tid - 128] = 0.f;
  __syncthreads();
  if (mlane == 0) {
#pragma unroll
    for (int r = 0; r < 4; ++r)
#pragma unroll
      for (int i = 0; i < 4; ++i)
        atomicAdd(&rsum[wr * 64 + r * 16 + q * 4 + i], rs[r][i]);
  }
  if (q == 0) {
#pragma unroll
    for (int c = 0; c < 4; ++c) atomicAdd(&csum[wc * 64 + c * 16 + mlane], cs[c]);
  }
  __syncthreads();
  if (tid < 128)
    atomicAdd(&rowlog[b * S_ + blockIdx.y * 128 + tid], rsum[tid]);
  else if (tid < 256)
    atomicAdd(&collog[b * S_ + blockIdx.x * 128 + (tid - 128)], csum[tid - 128]);
}

// ---------------- finalize: softmax(logits/256) -> weighted sums ------------
__device__ __forceinline__ float block_max(float v, float* buf, int tid) {
  buf[tid] = v; __syncthreads();
  for (int s = 128; s > 0; s >>= 1) {
    if (tid < s) buf[tid] = fmaxf(buf[tid], buf[tid + s]);
    __syncthreads();
  }
  float r = buf[0]; __syncthreads();
  return r;
}
__device__ __forceinline__ float block_sum(float v, float* buf, int tid) {
  buf[tid] = v; __syncthreads();
  for (int s = 128; s > 0; s >>= 1) {
    if (tid < s) buf[tid] = buf[tid] + buf[tid + s];
    __syncthreads();
  }
  float r = buf[0]; __syncthreads();
  return r;
}

__global__ __launch_bounds__(256) void finalize(
    const float* __restrict__ rowlog, const float* __restrict__ collog,
    const ushort* __restrict__ dg, const ushort* __restrict__ ug,
    float* __restrict__ out) {
  __shared__ float sd[S_], su[S_], buf[S_];
  const int b = blockIdx.x, tid = threadIdx.x;

  const float rowmean = rowlog[b * S_ + tid] * (1.f / (float)S_);
  const float colmean = collog[b * S_ + tid] * (1.f / (float)S_);

  float md = block_max(rowmean, buf, tid);
  float ed = __expf(rowmean - md);
  float sds = block_sum(ed, buf, tid);
  sd[tid] = ed / sds;
  float mu = block_max(colmean, buf, tid);
  float eu = __expf(colmean - mu);
  float sus = block_sum(eu, buf, tid);
  su[tid] = eu / sus;
  __syncthreads();

  const ushort* dgb = dg + (long)b * (S_ * OUT_F_);
  const ushort* ugb = ug + (long)b * (S_ * OUT_F_);
  float ad0 = 0.f, ad1 = 0.f, au0 = 0.f, au1 = 0.f;
  const int o = 2 * tid;
  for (int s = 0; s < S_; ++s) {
    const float wd = sd[s], wu = su[s];
    unsigned dv = *(const unsigned*)(dgb + s * OUT_F_ + o);
    unsigned uv = *(const unsigned*)(ugb + s * OUT_F_ + o);
    ad0 += wd * bf2f(dv & 0xffffu); ad1 += wd * bf2f(dv >> 16);
    au0 += wu * bf2f(uv & 0xffffu); au1 += wu * bf2f(uv >> 16);
  }
  out[b * OUT_F_ + o] = ad0;
  out[b * OUT_F_ + o + 1] = ad1;
  out[BSZ_ * OUT_F_ + b * OUT_F_ + o] = au0;
  out[BSZ_ * OUT_F_ + b * OUT_F_ + o + 1] = au1;
}

extern "C" void kernel_launch(void* const* d_in, const int* in_sizes, int n_in,
                              void* d_out, int out_size, void* d_ws, size_t ws_size,
                              hipStream_t stream) {
  (void)in_sizes; (void)n_in; (void)out_size; (void)ws_size;
  const float* Xd = (const float*)d_in[0];
  const float* Xu = (const float*)d_in[1];
  const float* Wd = (const float*)d_in[2];
  const float* bd = (const float*)d_in[3];
  const float* Wu = (const float*)d_in[4];
  const float* bu = (const float*)d_in[5];
  const float* W  = (const float*)d_in[6];
  float* out = (float*)d_out;
  char* ws = (char*)d_ws;

  // workspace layout (bytes). Peak ~103 MB.
  ushort* Xd_bf  = (ushort*)(ws + 0L);           // 33,554,432
  ushort* Xu_bf  = (ushort*)(ws + 33554432L);    // 16,777,216
  ushort* Wd_bf  = (ushort*)(ws + 50331648L);    //  1,048,576
  ushort* Wu_bf  = (ushort*)(ws + 51380224L);    //    524,288
  ushort* Wt_bf  = (ushort*)(ws + 51904512L);    //    524,288
  ushort* dg     = (ushort*)(ws + 52428800L);    // 16,777,216
  ushort* ug     = (ushort*)(ws + 69206016L);    // 16,777,216
  ushort* t_bf   = (ushort*)(ws + 85983232L);    // 16,777,216
  float*  rowlog = (float*)(ws + 102760448L);    //     65,536
  float*  collog = (float*)(ws + 102825984L);    //     65,536

  convert_bf16<<<16384, 256, 0, stream>>>(Xd, Xd_bf, 16777216L);
  convert_bf16<<<8192, 256, 0, stream>>>(Xu, Xu_bf, 8388608L);
  convert_bf16<<<512, 256, 0, stream>>>(Wd, Wd_bf, 524288L);
  convert_bf16<<<256, 256, 0, stream>>>(Wu, Wu_bf, 262144L);
  convert_transpose_w<<<1024, 256, 0, stream>>>(W, Wt_bf);
  zerof<<<128, 256, 0, stream>>>(rowlog, 32768);  // rowlog+collog contiguous

  dim3 blk(256);
  gemm_du<<<dim3(4, 128), blk, 0, stream>>>(Xd_bf, Wd_bf, bd, Xu_bf, Wu_bf, bu, dg, ug);
  gemm_t<<<dim3(4, 128), blk, 0, stream>>>(dg, Wt_bf, t_bf);
  gemm_att<<<dim3(2, 2, 64), blk, 0, stream>>>(t_bf, ug, rowlog, collog);
  finalize<<<64, 256, 0, stream>>>(rowlog, collog, dg, ug, out);
}